// Round 1
// baseline (431.241 us; speedup 1.0000x reference)
//
#include <hip/hip_runtime.h>
#include <stdint.h>

// Problem constants (from reference setup_inputs)
#define Bg    128
#define NPG   512
#define Cc    128
#define EPG   8192
#define Nn    (Bg*NPG)      // 65536
#define Ee    (Bg*EPG)      // 1048576
#define Kk    410           // ceil(0.8*512)
#define NKk   (Bg*Kk)       // 52480
#define SLOPE 0.2f
#define LAMBf 1.0f

// ---------------- Kernel 1: out-degree (weighted) + in-degree counts ----------------
__global__ __launch_bounds__(256) void k_count(const int* __restrict__ row,
                                               const int* __restrict__ col,
                                               const float* __restrict__ attr,
                                               float* __restrict__ deg,
                                               int* __restrict__ cnt) {
  int e = blockIdx.x * 256 + threadIdx.x;
  if (e < Ee) {
    atomicAdd(&deg[row[e]], attr[e]);
    atomicAdd(&cnt[col[e]], 1);
  }
}

// ---------------- Kernel 2: dis = deg>0 ? rsqrt(max(deg,1e-12)) : 0 ----------------
__global__ __launch_bounds__(256) void k_dis(const float* __restrict__ deg,
                                             float* __restrict__ dis) {
  int i = blockIdx.x * 256 + threadIdx.x;
  if (i < Nn) {
    float d = deg[i];
    dis[i] = (d > 0.f) ? rsqrtf(fmaxf(d, 1e-12f)) : 0.f;
  }
}

// ---------------- Generic single-block exclusive scan (n ints) ----------------
__global__ __launch_bounds__(1024) void k_scan(const int* __restrict__ in,
                                               int* __restrict__ offs,
                                               int* __restrict__ cursor, int n) {
  __shared__ int wsum[16];
  __shared__ int carry;
  if (threadIdx.x == 0) carry = 0;
  __syncthreads();
  int lane = threadIdx.x & 63, w = threadIdx.x >> 6;
  for (int base = 0; base < n; base += 1024) {
    int i = base + (int)threadIdx.x;
    int v = (i < n) ? in[i] : 0;
    int s = v;
    #pragma unroll
    for (int d = 1; d < 64; d <<= 1) { int t = __shfl_up(s, d, 64); if (lane >= d) s += t; }
    if (lane == 63) wsum[w] = s;
    __syncthreads();
    if (threadIdx.x < 16) {
      int t = wsum[threadIdx.x];
      #pragma unroll
      for (int d = 1; d < 16; d <<= 1) { int u = __shfl_up(t, d, 64); if ((int)threadIdx.x >= d) t += u; }
      wsum[threadIdx.x] = t;
    }
    __syncthreads();
    int incl = s + (w > 0 ? wsum[w - 1] : 0) + carry;
    if (i < n) { offs[i] = incl - v; cursor[i] = incl - v; }
    __syncthreads();                 // everyone has read carry & wsum
    if (threadIdx.x == 1023) carry = incl;
    __syncthreads();
  }
  if (threadIdx.x == 0) offs[n] = carry;
}

// ---------------- Kernel 4: scatter edges into dst-CSR with precomputed coef ----------------
__global__ __launch_bounds__(256) void k_scatter_csr(const int* __restrict__ row,
                                                     const int* __restrict__ col,
                                                     const float* __restrict__ attr,
                                                     const float* __restrict__ dis,
                                                     int* __restrict__ cursor,
                                                     int* __restrict__ csr_src,
                                                     float* __restrict__ csr_coef) {
  int e = blockIdx.x * 256 + threadIdx.x;
  if (e < Ee) {
    int r = row[e], c = col[e];
    int slot = atomicAdd(&cursor[c], 1);
    csr_src[slot] = r;
    csr_coef[slot] = dis[r] * attr[e] * dis[c];
  }
}

// ---------------- Kernel 5: score[i] = sum_c |x[i,c] - agg[i,c]|  (gather form) ----------------
// block 256 = 4 nodes x 64 lanes; each lane owns 2 channels (float2)
__global__ __launch_bounds__(256) void k_score(const float* __restrict__ x,
                                               const int* __restrict__ offs,
                                               const int* __restrict__ csr_src,
                                               const float* __restrict__ csr_coef,
                                               float* __restrict__ score) {
  int lane = threadIdx.x & 63;
  int node = blockIdx.x * 4 + (threadIdx.x >> 6);
  float2 xv = ((const float2*)(x + (size_t)node * Cc))[lane];
  float a0 = 0.f, a1 = 0.f;
  int s0 = offs[node], s1 = offs[node + 1];
  for (int s = s0; s < s1; ++s) {
    int src = csr_src[s];
    float cf = csr_coef[s];
    float2 xs = ((const float2*)(x + (size_t)src * Cc))[lane];
    a0 += cf * xs.x; a1 += cf * xs.y;
  }
  float v = fabsf(xv.x - a0) + fabsf(xv.y - a1);
  #pragma unroll
  for (int d = 32; d; d >>= 1) v += __shfl_xor(v, d, 64);
  if (lane == 0) score[node] = v;
}

// ---------------- Kernel 6: per-graph stable top-k via bitonic sort of 64-bit keys ----------------
// key = (~orderable(score) << 32) | local_idx  -> ascending sort == desc score, ties by idx
__global__ __launch_bounds__(512) void k_topk(const float* __restrict__ score,
                                              int* __restrict__ perm,
                                              int* __restrict__ mapping,
                                              float* __restrict__ batch_out) {
  __shared__ unsigned long long keys[NPG];
  int g = blockIdx.x;
  int t = threadIdx.x;
  float sc = score[g * NPG + t];
  unsigned u = __float_as_uint(sc);
  unsigned ord = (u & 0x80000000u) ? ~u : (u | 0x80000000u);
  keys[t] = ((unsigned long long)(~ord) << 32) | (unsigned)t;
  for (int k2 = 2; k2 <= NPG; k2 <<= 1) {
    for (int j2 = k2 >> 1; j2 > 0; j2 >>= 1) {
      __syncthreads();
      int ixj = t ^ j2;
      if (ixj > t) {
        unsigned long long a = keys[t], b = keys[ixj];
        bool up = ((t & k2) == 0);
        if ((a > b) == up) { keys[t] = b; keys[ixj] = a; }
      }
    }
  }
  __syncthreads();
  if (t < Kk) {
    int local = (int)(keys[t] & 0xFFFFFFFFu);
    int gn = g * NPG + local;
    int j = g * Kk + t;
    perm[j] = gn;
    mapping[gn] = j;
    batch_out[j] = (float)g;
  }
}

// ---------------- Kernel 7: x_pool gather + e1/e2 GEMV (fused) ----------------
__global__ __launch_bounds__(256) void k_feat(const float* __restrict__ x,
                                              const int* __restrict__ perm,
                                              const float* __restrict__ att,
                                              float* __restrict__ e1,
                                              float* __restrict__ e2,
                                              float* __restrict__ xpool) {
  int lane = threadIdx.x & 63;
  int j = blockIdx.x * 4 + (threadIdx.x >> 6);
  int g = perm[j];
  float2 xv = ((const float2*)(x + (size_t)g * Cc))[lane];
  ((float2*)(xpool + (size_t)j * Cc))[lane] = xv;
  float2 a1 = ((const float2*)att)[lane];
  float2 a2 = ((const float2*)(att + Cc))[lane];
  float s1 = xv.x * a1.x + xv.y * a1.y;
  float s2 = xv.x * a2.x + xv.y * a2.y;
  #pragma unroll
  for (int d = 32; d; d >>= 1) { s1 += __shfl_xor(s1, d, 64); s2 += __shfl_xor(s2, d, 64); }
  if (lane == 0) { e1[j] = s1; e2[j] = s2; }
}

// ---------------- Kernel 8/10: induced-adjacency row counts / scatter ----------------
__global__ __launch_bounds__(256) void k_icnt(const int* __restrict__ row,
                                              const int* __restrict__ col,
                                              const int* __restrict__ mapping,
                                              int* __restrict__ rcnt) {
  int e = blockIdx.x * 256 + threadIdx.x;
  if (e < Ee) {
    int mr = mapping[row[e]], mc = mapping[col[e]];
    if (mr >= 0 && mc >= 0) atomicAdd(&rcnt[mr], 1);
  }
}

__global__ __launch_bounds__(256) void k_iscatter(const int* __restrict__ row,
                                                  const int* __restrict__ col,
                                                  const float* __restrict__ attr,
                                                  const int* __restrict__ mapping,
                                                  int* __restrict__ rcursor,
                                                  int* __restrict__ icol,
                                                  float* __restrict__ ival) {
  int e = blockIdx.x * 256 + threadIdx.x;
  if (e < Ee) {
    int mr = mapping[row[e]], mc = mapping[col[e]];
    if (mr >= 0 && mc >= 0) {
      int slot = atomicAdd(&rcursor[mr], 1);
      icol[slot] = mc % Kk;
      ival[slot] = attr[e];
    }
  }
}

// ---------------- Kernel 11: fused W build + softmax + attn/new_edge_index writes ----------------
// block 256 = 4 waves, one pooled row per wave; row (410 floats) lives in LDS
#define RPAD 416
__global__ __launch_bounds__(256) void k_softmax(const float* __restrict__ e1,
                                                 const float* __restrict__ e2,
                                                 const int* __restrict__ roffs,
                                                 const int* __restrict__ icol,
                                                 const float* __restrict__ ival,
                                                 float* __restrict__ attn,
                                                 float* __restrict__ nrow,
                                                 float* __restrict__ ncol) {
  __shared__ float buf[4][RPAD];
  int lane = threadIdx.x & 63, w = threadIdx.x >> 6;
  int rowid = blockIdx.x * 4 + w;
  int b = rowid / Kk;
  float ev = e1[rowid];
  const float* e2g = e2 + b * Kk;
  for (int j = lane; j < Kk; j += 64) {
    float v = ev + e2g[j];
    v = (v > 0.f) ? v : SLOPE * v;
    buf[w][j] = v;
  }
  __syncthreads();
  int t0 = roffs[rowid], t1 = roffs[rowid + 1];
  for (int t = t0 + lane; t < t1; t += 64)
    atomicAdd(&buf[w][icol[t]], LAMBf * ival[t]);
  __syncthreads();
  float m = -1e30f;
  for (int j = lane; j < Kk; j += 64) m = fmaxf(m, buf[w][j]);
  #pragma unroll
  for (int d = 32; d; d >>= 1) m = fmaxf(m, __shfl_xor(m, d, 64));
  float s = 0.f;
  for (int j = lane; j < Kk; j += 64) {
    float ex = expf(buf[w][j] - m);
    buf[w][j] = ex;
    s += ex;
  }
  #pragma unroll
  for (int d = 32; d; d >>= 1) s += __shfl_xor(s, d, 64);
  float inv = 1.f / s;
  size_t base = (size_t)rowid * Kk;
  float frow = (float)rowid;
  for (int j = lane; j < Kk; j += 64) {
    attn[base + j] = buf[w][j] * inv;
    nrow[base + j] = frow;
    ncol[base + j] = (float)(b * Kk + j);
  }
}

// ---------------- host launch ----------------
extern "C" void kernel_launch(void* const* d_in, const int* in_sizes, int n_in,
                              void* d_out, int out_size, void* d_ws, size_t ws_size,
                              hipStream_t stream) {
  const float* x    = (const float*)d_in[0];
  const int*   row  = (const int*)d_in[1];
  const int*   col  = row + Ee;
  const float* attr = (const float*)d_in[2];
  const float* att  = (const float*)d_in[4];

  // workspace layout (bytes, 256-aligned)
  char* ws = (char*)d_ws;
  size_t off = 0;
  auto alloc = [&](size_t bytes) { char* p = ws + off; off = (off + bytes + 255) & ~(size_t)255; return p; };
  float* deg      = (float*)alloc((size_t)Nn * 4);
  float* dis      = (float*)alloc((size_t)Nn * 4);
  int*   cnt      = (int*)  alloc((size_t)Nn * 4);
  int*   offs     = (int*)  alloc((size_t)(Nn + 1) * 4);
  int*   cursor   = (int*)  alloc((size_t)Nn * 4);
  int*   csr_src  = (int*)  alloc((size_t)Ee * 4);
  float* csr_coef = (float*)alloc((size_t)Ee * 4);
  float* score    = (float*)alloc((size_t)Nn * 4);
  int*   perm     = (int*)  alloc((size_t)NKk * 4);
  int*   mapping  = (int*)  alloc((size_t)Nn * 4);
  float* e1       = (float*)alloc((size_t)NKk * 4);
  float* e2       = (float*)alloc((size_t)NKk * 4);
  int*   rcnt     = (int*)  alloc((size_t)NKk * 4);
  int*   roffs    = (int*)  alloc((size_t)(NKk + 1) * 4);
  int*   rcursor  = (int*)  alloc((size_t)NKk * 4);
  int*   icol     = (int*)  alloc((size_t)Ee * 4);
  float* ival     = (float*)alloc((size_t)Ee * 4);

  // output layout: x_pool | new_row | new_col | attn | batch_pool (all fp32)
  float* out      = (float*)d_out;
  float* o_xpool  = out;
  float* o_nrow   = o_xpool + (size_t)NKk * Cc;
  float* o_ncol   = o_nrow + (size_t)NKk * Kk;
  float* o_attn   = o_ncol + (size_t)NKk * Kk;
  float* o_batch  = o_attn + (size_t)NKk * Kk;

  hipMemsetAsync(deg, 0, (size_t)Nn * 4, stream);
  hipMemsetAsync(cnt, 0, (size_t)Nn * 4, stream);
  hipMemsetAsync(rcnt, 0, (size_t)NKk * 4, stream);
  hipMemsetAsync(mapping, 0xFF, (size_t)Nn * 4, stream);   // -1

  k_count<<<Ee / 256, 256, 0, stream>>>(row, col, attr, deg, cnt);
  k_dis<<<Nn / 256, 256, 0, stream>>>(deg, dis);
  k_scan<<<1, 1024, 0, stream>>>(cnt, offs, cursor, Nn);
  k_scatter_csr<<<Ee / 256, 256, 0, stream>>>(row, col, attr, dis, cursor, csr_src, csr_coef);
  k_score<<<Nn / 4, 256, 0, stream>>>(x, offs, csr_src, csr_coef, score);
  k_topk<<<Bg, 512, 0, stream>>>(score, perm, mapping, o_batch);
  k_feat<<<NKk / 4, 256, 0, stream>>>(x, perm, att, e1, e2, o_xpool);
  k_icnt<<<Ee / 256, 256, 0, stream>>>(row, col, mapping, rcnt);
  k_scan<<<1, 1024, 0, stream>>>(rcnt, roffs, rcursor, NKk);
  k_iscatter<<<Ee / 256, 256, 0, stream>>>(row, col, attr, mapping, rcursor, icol, ival);
  k_softmax<<<NKk / 4, 256, 0, stream>>>(e1, e2, roffs, icol, ival, o_attn, o_nrow, o_ncol);
}

// Round 2
// 198.845 us; speedup vs baseline: 2.1687x; 2.1687x over previous
//
#include <hip/hip_runtime.h>
#include <stdint.h>

// Problem constants (from reference setup_inputs)
#define Bg    128
#define NPG   512
#define Cc    128
#define EPG   8192
#define Nn    (Bg*NPG)      // 65536
#define Ee    (Bg*EPG)      // 1048576
#define Kk    410           // ceil(0.8*512)
#define NKk   (Bg*Kk)       // 52480
#define ROFFS_STRIDE 411    // per-graph row-offset stride (410 rows + end sentinel)
#define SLOPE 0.2f

// ---------- LDS exclusive scan over 512 ints, 512 threads ----------
__device__ __forceinline__ void scan512(int* buf, int* ws) {
  int t = threadIdx.x, lane = t & 63, w = t >> 6;
  int v = buf[t];
  int s = v;
  #pragma unroll
  for (int d = 1; d < 64; d <<= 1) { int u = __shfl_up(s, d, 64); if (lane >= d) s += u; }
  if (lane == 63) ws[w] = s;
  __syncthreads();
  if (t < 8) {
    int u = ws[t];
    #pragma unroll
    for (int d = 1; d < 8; d <<= 1) { int u2 = __shfl_up(u, d, 64); if (t >= d) u += u2; }
    ws[t] = u;
  }
  __syncthreads();
  int excl = s - v + (w ? ws[w - 1] : 0);
  buf[t] = excl;          // each thread touches only its own slot
  __syncthreads();
}

// ---------- K1: per-graph fused {deg, dis, in-count, scan, dst-CSR scatter} ----------
// one block (512 thr) per graph; all counts/cursors/deg in LDS
__global__ __launch_bounds__(512) void k_build_csr(const int* __restrict__ row,
                                                   const int* __restrict__ col,
                                                   const float* __restrict__ attr,
                                                   int* __restrict__ offs,
                                                   int* __restrict__ csr_src,
                                                   float* __restrict__ csr_coef) {
  __shared__ int cnt[512];
  __shared__ int cur[512];
  __shared__ float degL[512];
  __shared__ float disL[512];
  __shared__ int ws[8];
  int g = blockIdx.x, t = threadIdx.x, base = g * NPG;
  const int*   rowg  = row  + g * EPG;
  const int*   colg  = col  + g * EPG;
  const float* attrg = attr + g * EPG;
  cnt[t] = 0; degL[t] = 0.f;
  __syncthreads();
  for (int i = t; i < EPG; i += 512) {
    atomicAdd(&cnt[colg[i] - base], 1);
    atomicAdd(&degL[rowg[i] - base], attrg[i]);
  }
  __syncthreads();
  float d = degL[t];
  disL[t] = (d > 0.f) ? rsqrtf(fmaxf(d, 1e-12f)) : 0.f;
  scan512(cnt, ws);                       // cnt := exclusive offsets (graph-local)
  offs[base + t] = g * EPG + cnt[t];
  if (t == 0) offs[base + NPG] = g * EPG + EPG;  // duplicate of next block's entry / final sentinel
  cur[t] = cnt[t];
  __syncthreads();
  for (int i = t; i < EPG; i += 512) {
    int s = rowg[i] - base, c = colg[i] - base;
    int slot = atomicAdd(&cur[c], 1);
    csr_src[g * EPG + slot]  = rowg[i];                          // global src node id
    csr_coef[g * EPG + slot] = disL[s] * attrg[i] * disL[c];
  }
}

// ---------- K2: score[i] = sum_c |x[i,c] - agg[i,c]| (gather over dst-CSR) ----------
// one wave per node, 2 channels per lane, 2-way unrolled gather
__global__ __launch_bounds__(256) void k_score(const float* __restrict__ x,
                                               const int* __restrict__ offs,
                                               const int* __restrict__ csr_src,
                                               const float* __restrict__ csr_coef,
                                               float* __restrict__ score) {
  int lane = threadIdx.x & 63;
  int node = blockIdx.x * 4 + (threadIdx.x >> 6);
  const float2* xp = (const float2*)x;
  float2 xv = xp[(size_t)node * 64 + lane];
  int s0 = offs[node], s1 = offs[node + 1];
  float a0 = 0.f, a1 = 0.f, b0 = 0.f, b1 = 0.f;
  int s = s0;
  for (; s + 2 <= s1; s += 2) {
    int   i0 = csr_src[s],     i1 = csr_src[s + 1];
    float c0 = csr_coef[s],    c1 = csr_coef[s + 1];
    float2 v0 = xp[(size_t)i0 * 64 + lane];
    float2 v1 = xp[(size_t)i1 * 64 + lane];
    a0 += c0 * v0.x; a1 += c0 * v0.y;
    b0 += c1 * v1.x; b1 += c1 * v1.y;
  }
  if (s < s1) {
    int i0 = csr_src[s]; float c0 = csr_coef[s];
    float2 v0 = xp[(size_t)i0 * 64 + lane];
    a0 += c0 * v0.x; a1 += c0 * v0.y;
  }
  float v = fabsf(xv.x - a0 - b0) + fabsf(xv.y - a1 - b1);
  #pragma unroll
  for (int d = 32; d; d >>= 1) v += __shfl_xor(v, d, 64);
  if (lane == 0) score[node] = v;
}

// ---------- K3: per-graph fused {stable top-k bitonic sort, perm/batch, induced CSR} ----------
__global__ __launch_bounds__(512) void k_topk_induced(const float* __restrict__ score,
                                                      const int* __restrict__ row,
                                                      const int* __restrict__ col,
                                                      const float* __restrict__ attr,
                                                      int* __restrict__ perm,
                                                      float* __restrict__ batch_out,
                                                      int* __restrict__ roffs,
                                                      int* __restrict__ icol,
                                                      float* __restrict__ ival) {
  __shared__ unsigned long long keys[512];
  __shared__ int mapL[512];
  __shared__ int rcnt[512];
  __shared__ int rcur[512];
  __shared__ int ws[8];
  int g = blockIdx.x, t = threadIdx.x, base = g * NPG;
  // key: ascending sort == descending score, ties by smaller idx (stable argsort match)
  float sc = score[base + t];
  unsigned u = __float_as_uint(sc);
  unsigned ord = (u & 0x80000000u) ? ~u : (u | 0x80000000u);
  keys[t] = ((unsigned long long)(~ord) << 32) | (unsigned)t;
  for (int k2 = 2; k2 <= 512; k2 <<= 1) {
    for (int j2 = k2 >> 1; j2 > 0; j2 >>= 1) {
      __syncthreads();
      int ixj = t ^ j2;
      if (ixj > t) {
        unsigned long long a = keys[t], b = keys[ixj];
        bool up = ((t & k2) == 0);
        if ((a > b) == up) { keys[t] = b; keys[ixj] = a; }
      }
    }
  }
  __syncthreads();
  int local = (int)(keys[t] & 0xFFFFFFFFu);
  mapL[local] = (t < Kk) ? t : -1;          // graph-local pooled index or -1
  if (t < Kk) {
    perm[g * Kk + t] = base + local;
    batch_out[g * Kk + t] = (float)g;
  }
  rcnt[t] = 0;
  __syncthreads();
  const int*   rowg  = row  + g * EPG;
  const int*   colg  = col  + g * EPG;
  const float* attrg = attr + g * EPG;
  for (int i = t; i < EPG; i += 512) {
    int mr = mapL[rowg[i] - base], mc = mapL[colg[i] - base];
    if (mr >= 0 && mc >= 0) atomicAdd(&rcnt[mr], 1);
  }
  __syncthreads();
  scan512(rcnt, ws);
  if (t <= Kk) roffs[g * ROFFS_STRIDE + t] = g * EPG + rcnt[t];  // t==Kk is the end sentinel
  rcur[t] = rcnt[t];
  __syncthreads();
  for (int i = t; i < EPG; i += 512) {
    int mr = mapL[rowg[i] - base], mc = mapL[colg[i] - base];
    if (mr >= 0 && mc >= 0) {
      int slot = atomicAdd(&rcur[mr], 1);
      icol[g * EPG + slot] = mc;
      ival[g * EPG + slot] = attrg[i];
    }
  }
}

// ---------- K4: x_pool gather + e1/e2 GEMV (fused) ----------
__global__ __launch_bounds__(256) void k_feat(const float* __restrict__ x,
                                              const int* __restrict__ perm,
                                              const float* __restrict__ att,
                                              float* __restrict__ e1,
                                              float* __restrict__ e2,
                                              float* __restrict__ xpool) {
  int lane = threadIdx.x & 63;
  int j = blockIdx.x * 4 + (threadIdx.x >> 6);
  int gsrc = perm[j];
  float2 xv = ((const float2*)x)[(size_t)gsrc * 64 + lane];
  ((float2*)xpool)[(size_t)j * 64 + lane] = xv;
  float2 a1 = ((const float2*)att)[lane];
  float2 a2 = ((const float2*)(att + Cc))[lane];
  float s1 = xv.x * a1.x + xv.y * a1.y;
  float s2 = xv.x * a2.x + xv.y * a2.y;
  #pragma unroll
  for (int d = 32; d; d >>= 1) { s1 += __shfl_xor(s1, d, 64); s2 += __shfl_xor(s2, d, 64); }
  if (lane == 0) { e1[j] = s1; e2[j] = s2; }
}

// ---------- K5: fused W build + softmax + attn/new_row/new_col writes ----------
// one wave per pooled row; row (410 f32) in LDS; float2 stores
__global__ __launch_bounds__(256) void k_softmax(const float* __restrict__ e1,
                                                 const float* __restrict__ e2,
                                                 const int* __restrict__ roffs,
                                                 const int* __restrict__ icol,
                                                 const float* __restrict__ ival,
                                                 float* __restrict__ attn,
                                                 float* __restrict__ nrow,
                                                 float* __restrict__ ncol) {
  __shared__ float buf[4][412];
  int lane = threadIdx.x & 63, w = threadIdx.x >> 6;
  int rowid = blockIdx.x * 4 + w;
  int b = rowid / Kk;
  int r = rowid - b * Kk;
  float ev = e1[rowid];
  const float* e2g = e2 + b * Kk;
  for (int j = lane; j < Kk; j += 64) {
    float v = ev + e2g[j];
    buf[w][j] = (v > 0.f) ? v : SLOPE * v;
  }
  __syncthreads();
  int t0 = roffs[b * ROFFS_STRIDE + r], t1 = roffs[b * ROFFS_STRIDE + r + 1];
  for (int p = t0 + lane; p < t1; p += 64)
    atomicAdd(&buf[w][icol[p]], ival[p]);          // LAMB = 1.0
  __syncthreads();
  float m = -1e30f;
  for (int j = lane; j < Kk; j += 64) m = fmaxf(m, buf[w][j]);
  #pragma unroll
  for (int d = 32; d; d >>= 1) m = fmaxf(m, __shfl_xor(m, d, 64));
  float s = 0.f;
  for (int j = lane; j < Kk; j += 64) {
    float ex = __expf(buf[w][j] - m);
    buf[w][j] = ex;
    s += ex;
  }
  #pragma unroll
  for (int d = 32; d; d >>= 1) s += __shfl_xor(s, d, 64);
  float inv = 1.f / s;
  size_t fb = (size_t)rowid * Kk;
  float2* ap = (float2*)(attn + fb);
  float2* nr = (float2*)(nrow + fb);
  float2* nc = (float2*)(ncol + fb);
  float frow  = (float)rowid;
  float cbase = (float)(b * Kk);
  for (int p = lane; p < Kk / 2; p += 64) {
    int j = 2 * p;
    ap[p] = make_float2(buf[w][j] * inv, buf[w][j + 1] * inv);
    nr[p] = make_float2(frow, frow);
    nc[p] = make_float2(cbase + j, cbase + j + 1);
  }
}

// ---------------- host launch ----------------
extern "C" void kernel_launch(void* const* d_in, const int* in_sizes, int n_in,
                              void* d_out, int out_size, void* d_ws, size_t ws_size,
                              hipStream_t stream) {
  const float* x    = (const float*)d_in[0];
  const int*   row  = (const int*)d_in[1];
  const int*   col  = row + Ee;
  const float* attr = (const float*)d_in[2];
  const float* att  = (const float*)d_in[4];

  char* ws = (char*)d_ws;
  size_t off = 0;
  auto alloc = [&](size_t bytes) { char* p = ws + off; off = (off + bytes + 255) & ~(size_t)255; return p; };
  int*   offs     = (int*)  alloc((size_t)(Nn + 1) * 4);
  int*   csr_src  = (int*)  alloc((size_t)Ee * 4);
  float* csr_coef = (float*)alloc((size_t)Ee * 4);
  float* score    = (float*)alloc((size_t)Nn * 4);
  int*   perm     = (int*)  alloc((size_t)NKk * 4);
  int*   roffs    = (int*)  alloc((size_t)Bg * ROFFS_STRIDE * 4);
  int*   icol     = (int*)  alloc((size_t)Ee * 4);
  float* ival     = (float*)alloc((size_t)Ee * 4);
  float* e1       = (float*)alloc((size_t)NKk * 4);
  float* e2       = (float*)alloc((size_t)NKk * 4);

  // output layout: x_pool | new_row | new_col | attn | batch_pool (all fp32)
  float* out      = (float*)d_out;
  float* o_xpool  = out;
  float* o_nrow   = o_xpool + (size_t)NKk * Cc;
  float* o_ncol   = o_nrow + (size_t)NKk * Kk;
  float* o_attn   = o_ncol + (size_t)NKk * Kk;
  float* o_batch  = o_attn + (size_t)NKk * Kk;

  k_build_csr  <<<Bg,      512, 0, stream>>>(row, col, attr, offs, csr_src, csr_coef);
  k_score      <<<Nn / 4,  256, 0, stream>>>(x, offs, csr_src, csr_coef, score);
  k_topk_induced<<<Bg,     512, 0, stream>>>(score, row, col, attr, perm, o_batch, roffs, icol, ival);
  k_feat       <<<NKk / 4, 256, 0, stream>>>(x, perm, att, e1, e2, o_xpool);
  k_softmax    <<<NKk / 4, 256, 0, stream>>>(e1, e2, roffs, icol, ival, o_attn, o_nrow, o_ncol);
}